// Round 3
// baseline (341.213 us; speedup 1.0000x reference)
//
#include <hip/hip_runtime.h>

#define NB 16
#define NVEC 2048
#define NDIM 32
#define NW 4
#define NHID 128
#define NCLASS 10
#define MS 16
#define USIZE (129 * 32)    // final U per b: rows 0..127 = fw2@V, row 128 = fb2^T@V
#define UPSZ  (128 * 32)    // partial U slot (bias row handled in k_Ured)

// tanh-approx GELU; validated absmax vs ref in prior sessions.
__device__ __forceinline__ float gelu_fast(float x) {
    float t = 1.5957691216057308f * x * (1.0f + 0.044715f * x * x);
    return x / (1.0f + __expf(-t));
}

// ---------------------------------------------------------------------------
// Embed gather (float4) + out=bias init. grid 1024 x 256.
__global__ __launch_bounds__(256) void k_embed(const int* __restrict__ data,
                                               const float* __restrict__ emb,
                                               const float* __restrict__ bf,
                                               float* __restrict__ X,
                                               float* __restrict__ out) {
    int gid = blockIdx.x * 256 + threadIdx.x;      // NB*NVEC*NDIM/4 = 262144
    int row = gid >> 3, sub = gid & 7;             // 8 float4 per 32-float row
    ((float4*)X)[gid] = ((const float4*)emb)[data[row] * 8 + sub];
    if (blockIdx.x == 0 && threadIdx.x < NB * NCLASS)
        out[threadIdx.x] = bf[threadIdx.x % NCLASS];
}

// ---------------------------------------------------------------------------
// Partial U = fw2 @ V, m-split. grid (MS, NB) x 256.
// Wave (kh, mh): lanes own k = kh*64+lane, all 32 d in registers.
// fw2 row slice per-lane in VGPRs; V rows via wave-uniform loads (s_load path:
// indices contain no threadIdx -- wave id via readfirstlane). LDS only for the
// 2-way mh merge. R2 post-mortem: LDS pipe (1/CU, ~12cyc/b128) was the
// bottleneck; this kernel now issues ~70 LDS instr/block instead of ~2000.
__global__ __launch_bounds__(256) void k_U(const float* __restrict__ V,
                                           const float* __restrict__ fw2,
                                           float* __restrict__ Upart) {
    __shared__ float part[2][64 * 32];   // [kh][d*64 + klocal], 16 KB
    int ms = blockIdx.x, b = blockIdx.y;
    int tid = threadIdx.x, lane = tid & 63;
    int wv = __builtin_amdgcn_readfirstlane(tid >> 6);   // 0..3, SGPR
    int kh = wv & 1, mh = wv >> 1;
    int k = kh * 64 + lane;
    int m0 = ms * 128 + mh * 64;

    // per-lane fw2 slice: fw2[k][m0 .. m0+64)
    float wreg[64];
    {
        const float4* wr = (const float4*)(fw2 + (size_t)k * NVEC + m0);
#pragma unroll
        for (int j = 0; j < 16; ++j) {
            float4 v = wr[j];
            wreg[4 * j] = v.x; wreg[4 * j + 1] = v.y;
            wreg[4 * j + 2] = v.z; wreg[4 * j + 3] = v.w;
        }
    }
    float acc[32];
#pragma unroll
    for (int d = 0; d < 32; ++d) acc[d] = 0.f;

    const float4* Vr = (const float4*)(V + ((size_t)b * NVEC + m0) * NDIM);  // uniform
#pragma unroll 2
    for (int mm = 0; mm < 64; ++mm) {
        float w = wreg[mm];
        float4 vv[8];
#pragma unroll
        for (int j = 0; j < 8; ++j) vv[j] = Vr[mm * 8 + j];   // wave-uniform -> s_load
#pragma unroll
        for (int j = 0; j < 8; ++j) {
            acc[4 * j + 0] += w * vv[j].x;
            acc[4 * j + 1] += w * vv[j].y;
            acc[4 * j + 2] += w * vv[j].z;
            acc[4 * j + 3] += w * vv[j].w;
        }
    }
    if (mh == 1) {
#pragma unroll
        for (int d = 0; d < 32; ++d) part[kh][d * 64 + lane] = acc[d];
    }
    __syncthreads();
    if (mh == 0) {
#pragma unroll
        for (int d = 0; d < 32; ++d) acc[d] += part[kh][d * 64 + lane];
        float* Up = Upart + ((size_t)ms * NB + b) * UPSZ;
#pragma unroll
        for (int j = 0; j < 8; ++j)
            *(float4*)&Up[k * 32 + j * 4] =
                make_float4(acc[4 * j], acc[4 * j + 1], acc[4 * j + 2], acc[4 * j + 3]);
    }
}

// ---------------------------------------------------------------------------
// Reduce MS partials into final U + compute bias row fb2^T @ V.
// grid (NB, 9) x 256: y<8 -> 128 float4 of U each; y==8 -> bias row.
__global__ __launch_bounds__(256) void k_Ured(const float* __restrict__ Upart,
                                              const float* __restrict__ V,
                                              const float* __restrict__ fb2,
                                              float* __restrict__ U) {
    int b = blockIdx.x, y = blockIdx.y;
    int tid = threadIdx.x;
    if (y < 8) {
        if (tid < 128) {
            int i4 = y * 128 + tid;            // UPSZ/4 = 1024 = 8*128
            float4 s = ((const float4*)(Upart + (size_t)b * UPSZ))[i4];
#pragma unroll
            for (int ms = 1; ms < MS; ++ms) {
                float4 v = ((const float4*)(Upart + ((size_t)ms * NB + b) * UPSZ))[i4];
                s.x += v.x; s.y += v.y; s.z += v.z; s.w += v.w;
            }
            ((float4*)(U + (size_t)b * USIZE))[i4] = s;
        }
    } else {
        __shared__ float red[8][33];
        int d = tid & 31, seg = tid >> 5;
        float ca = 0.f;
        for (int m = seg * 256; m < seg * 256 + 256; ++m)
            ca += fb2[m] * V[((size_t)b * NVEC + m) * NDIM + d];   // fb2 uniform -> s_load
        red[seg][d] = ca;
        __syncthreads();
        if (tid < 32) {
            float s = 0.f;
#pragma unroll
            for (int j = 0; j < 8; ++j) s += red[j][tid];
            U[(size_t)b * USIZE + 128 * 32 + tid] = s;
        }
    }
}

// ---------------------------------------------------------------------------
// Fused h+apply. grid (NVEC/128, NB) x 256. Wave (rg, kh):
//  h-phase: lane owns k-column kf (fw1 col in 32 VGPRs), X rows via s_load,
//           64 rows per wave, h -> LDS (conflict-free).
//  apply:   lane owns row rowA, 32-d accumulator in regs; U rows via s_load
//           (1 SGPR operand per FMA is free); k-halves merged via LDS.
// LAST: classifier fused in-register. LDS 66 KB.
template <bool LAST>
__global__ __launch_bounds__(256) void k_applyF(const float* __restrict__ X,
                                                const float* __restrict__ fw1l,
                                                const float* __restrict__ fb1l,
                                                const float* __restrict__ U,
                                                float* __restrict__ Vout,
                                                const float* __restrict__ Wf,
                                                float* __restrict__ out) {
    __shared__ float hsm[128 * 129];     // 66 KB; reused for the kh-merge
    int ng = blockIdx.x, b = blockIdx.y;
    int tid = threadIdx.x, lane = tid & 63;
    int wv = __builtin_amdgcn_readfirstlane(tid >> 6);   // 0..3
    int rg = wv >> 1, kh = wv & 1;
    int n0 = ng * 128;
    int kf = kh * 64 + lane;

    // per-lane fw1 column kf + bias
    float w1reg[32];
#pragma unroll
    for (int d = 0; d < 32; ++d) w1reg[d] = fw1l[d * NHID + kf];
    float b1 = fb1l[kf];

    // ---- h-phase: 64 rows, 1 k per lane
    const float* Xb = X + ((size_t)b * NVEC + n0 + rg * 64) * NDIM;
    for (int rr = 0; rr < 64; rr += 2) {
        const float4* x0 = (const float4*)(Xb + rr * 32);        // uniform -> s_load
        const float4* x1 = (const float4*)(Xb + rr * 32 + 32);
        float a0 = b1, a0b = 0.f, a1 = b1, a1b = 0.f;
#pragma unroll
        for (int j = 0; j < 8; ++j) {
            float4 v0 = x0[j], v1 = x1[j];
            a0  += v0.x * w1reg[4 * j + 0];
            a0b += v0.y * w1reg[4 * j + 1];
            a0  += v0.z * w1reg[4 * j + 2];
            a0b += v0.w * w1reg[4 * j + 3];
            a1  += v1.x * w1reg[4 * j + 0];
            a1b += v1.y * w1reg[4 * j + 1];
            a1  += v1.z * w1reg[4 * j + 2];
            a1b += v1.w * w1reg[4 * j + 3];
        }
        int r = rg * 64 + rr;
        hsm[r * 129 + kf]       = gelu_fast(a0 + a0b);
        hsm[(r + 1) * 129 + kf] = gelu_fast(a1 + a1b);
    }
    __syncthreads();

    // ---- apply: lane = row, k-half per wave
    float oacc[32];
#pragma unroll
    for (int d = 0; d < 32; ++d) oacc[d] = 0.f;
    int rowA = rg * 64 + lane;
    const float* hrow = &hsm[rowA * 129 + kh * 64];
    const float4* Ub4 = (const float4*)(U + (size_t)b * USIZE) + (size_t)kh * 64 * 8;
#pragma unroll 2
    for (int kk = 0; kk < 64; ++kk) {
        float hv = hrow[kk];                 // ds_read_b32, stride 129 -> conflict-free
        float4 uu[8];
#pragma unroll
        for (int j = 0; j < 8; ++j) uu[j] = Ub4[kk * 8 + j];   // uniform -> s_load
#pragma unroll
        for (int j = 0; j < 8; ++j) {
            oacc[4 * j + 0] += hv * uu[j].x;
            oacc[4 * j + 1] += hv * uu[j].y;
            oacc[4 * j + 2] += hv * uu[j].z;
            oacc[4 * j + 3] += hv * uu[j].w;
        }
    }
    __syncthreads();                         // hsm reads done
    if (kh == 1) {
#pragma unroll
        for (int d = 0; d < 32; ++d) hsm[rowA * 33 + d] = oacc[d];  // (lane+d)%32 banks
    }
    __syncthreads();
    if (kh == 0) {
        const float4* Ubias = (const float4*)(U + (size_t)b * USIZE + 128 * 32);
#pragma unroll
        for (int j = 0; j < 8; ++j) {
            float4 ub = Ubias[j];
            oacc[4 * j + 0] += hsm[rowA * 33 + 4 * j + 0] + ub.x;
            oacc[4 * j + 1] += hsm[rowA * 33 + 4 * j + 1] + ub.y;
            oacc[4 * j + 2] += hsm[rowA * 33 + 4 * j + 2] + ub.z;
            oacc[4 * j + 3] += hsm[rowA * 33 + 4 * j + 3] + ub.w;
        }
        if constexpr (!LAST) {
            float* vo = Vout + ((size_t)b * NVEC + n0 + rowA) * NDIM;
#pragma unroll
            for (int j = 0; j < 8; ++j)
                *(float4*)&vo[j * 4] = make_float4(oacc[4 * j], oacc[4 * j + 1],
                                                   oacc[4 * j + 2], oacc[4 * j + 3]);
        } else {
            float accC[NCLASS];
#pragma unroll
            for (int c = 0; c < NCLASS; ++c) accC[c] = 0.f;
            int nrow = n0 + rowA;
#pragma unroll
            for (int d = 0; d < 32; ++d) {
                float v = oacc[d];
                const float2* wr = (const float2*)(Wf + ((size_t)nrow * 32 + d) * NCLASS);
#pragma unroll
                for (int p = 0; p < 5; ++p) {
                    float2 w = wr[p];
                    accC[2 * p]     += v * w.x;
                    accC[2 * p + 1] += v * w.y;
                }
            }
#pragma unroll
            for (int c = 0; c < NCLASS; ++c)
#pragma unroll
                for (int off = 32; off >= 1; off >>= 1)
                    accC[c] += __shfl_down(accC[c], off, 64);
            if (lane == 0) {
#pragma unroll
                for (int c = 0; c < NCLASS; ++c)
                    atomicAdd(&out[b * NCLASS + c], accC[c]);
            }
        }
    }
}

// ---------------------------------------------------------------------------
extern "C" void kernel_launch(void* const* d_in, const int* in_sizes, int n_in,
                              void* d_out, int out_size, void* d_ws, size_t ws_size,
                              hipStream_t stream) {
    const int*   data = (const int*)d_in[0];
    const float* emb  = (const float*)d_in[1];
    const float* fw1  = (const float*)d_in[2];
    const float* fb1  = (const float*)d_in[3];
    const float* fw2  = (const float*)d_in[4];
    const float* fb2  = (const float*)d_in[5];
    const float* Wf   = (const float*)d_in[6];
    const float* bf   = (const float*)d_in[7];
    float* out = (float*)d_out;

    float* X     = (float*)d_ws;                      // 1048576 floats
    float* VA    = X + NB * NVEC * NDIM;              // 1048576
    float* VB    = VA + NB * NVEC * NDIM;             // 1048576
    float* Upart = VB + NB * NVEC * NDIM;             // MS*NB*UPSZ = 1048576
    float* U     = Upart + (size_t)MS * NB * UPSZ;    // NB*USIZE = 66048

    k_embed<<<dim3(NB * NVEC * NDIM / 4 / 256), 256, 0, stream>>>(data, emb, bf, X, out);

    const float* Vcur = X;
    float* Vnext = VA;
    for (int t = 0; t < NW; ++t) {
        int i = NW - 1 - t;
        k_U<<<dim3(MS, NB), 256, 0, stream>>>(Vcur, fw2 + (size_t)i * NHID * NVEC, Upart);
        k_Ured<<<dim3(NB, 9), 256, 0, stream>>>(Upart, Vcur, fb2 + (size_t)i * NVEC, U);
        if (i > 0) {
            k_applyF<false><<<dim3(NVEC / 128, NB), 256, 0, stream>>>(
                X, fw1 + (size_t)i * NDIM * NHID, fb1 + (size_t)i * NHID,
                U, Vnext, nullptr, nullptr);
            Vcur = Vnext;
            Vnext = (Vnext == VA) ? VB : VA;
        } else {
            k_applyF<true><<<dim3(NVEC / 128, NB), 256, 0, stream>>>(
                X, fw1, fb1, U, nullptr, Wf, out);
        }
    }
}

// Round 4
// 223.092 us; speedup vs baseline: 1.5295x; 1.5295x over previous
//
#include <hip/hip_runtime.h>

#define NB 16
#define NVEC 2048
#define NDIM 32
#define NW 4
#define NHID 128
#define NCLASS 10
#define MS 16
#define USIZE (129 * 32)    // final U per b: rows 0..127 = fw2@V, row 128 = fb2^T@V
#define UPSZ  (128 * 32)    // partial U slot

// tanh-approx GELU; validated absmax vs ref in prior sessions.
__device__ __forceinline__ float gelu_fast(float x) {
    float t = 1.5957691216057308f * x * (1.0f + 0.044715f * x * x);
    return x / (1.0f + __expf(-t));
}

// ---------------------------------------------------------------------------
// Embed gather (float4) + out=bias init. grid 1024 x 256.
__global__ __launch_bounds__(256) void k_embed(const int* __restrict__ data,
                                               const float* __restrict__ emb,
                                               const float* __restrict__ bf,
                                               float* __restrict__ X,
                                               float* __restrict__ out) {
    int gid = blockIdx.x * 256 + threadIdx.x;      // NB*NVEC*NDIM/4 = 262144
    int row = gid >> 3, sub = gid & 7;
    ((float4*)X)[gid] = ((const float4*)emb)[data[row] * 8 + sub];
    if (blockIdx.x == 0 && threadIdx.x < NB * NCLASS)
        out[threadIdx.x] = bf[threadIdx.x % NCLASS];
}

// ---------------------------------------------------------------------------
// Partial U = fw2 @ V, m-split. grid (MS, NB) x 256, 1 block/CU.
// Thread tile 4k x 4d with INTERLEAVED k (k = kg + 32*i, kg = lane):
// fw2s reads at row-stride 132 -> lane residues 4*lane mod 128 = uniform
// banks (R3 post-mortem: quad-blocked k gave 2 residues -> conflicts;
// wave-uniform GLOBAL loads gave exposed latency -> broadcasts now from LDS).
// Per 4-m step: 4 uniform b128 + 4 broadcast b128 per 64 FMA-instr.
__global__ __launch_bounds__(256) void k_U(const float* __restrict__ V,
                                           const float* __restrict__ fw2,
                                           float* __restrict__ Upart) {
    __shared__ float fw2s[128 * 132];   // [k][m] pad 132, 67.6 KB
    __shared__ float Vs[128 * 32];      // [m][d], broadcast reads
    int ms = blockIdx.x, b = blockIdx.y;
    int tid = threadIdx.x;
    int m0 = ms * 128;

    {   // stage V chunk (16 KB), linear float4
        const float4* Vg = (const float4*)(V + ((size_t)b * NVEC + m0) * NDIM);
#pragma unroll
        for (int j = 0; j < 4; ++j)
            ((float4*)Vs)[tid + 256 * j] = Vg[tid + 256 * j];
    }
    {   // stage fw2 block [128k][128m]; write stride 132 -> uniform banks
        int row = tid & 127, half = tid >> 7;
        const float4* fg = (const float4*)(fw2 + (size_t)row * NVEC + m0 + 64 * half);
        float4* fs = (float4*)(fw2s + row * 132 + 64 * half);
#pragma unroll
        for (int q = 0; q < 16; ++q) fs[q] = fg[q];
    }
    __syncthreads();

    int kg = tid & 31, dg = tid >> 5;
    int d0 = dg * 4;
    float acc[4][4];
#pragma unroll
    for (int i = 0; i < 4; ++i)
#pragma unroll
        for (int j = 0; j < 4; ++j) acc[i][j] = 0.f;

    for (int mm = 0; mm < 128; mm += 4) {
        float4 w[4], v[4];
#pragma unroll
        for (int i = 0; i < 4; ++i)
            w[i] = *(const float4*)&fw2s[(kg + 32 * i) * 132 + mm];   // uniform banks
#pragma unroll
        for (int j = 0; j < 4; ++j)
            v[j] = *(const float4*)&Vs[(mm + j) * 32 + d0];           // 2-addr broadcast
#pragma unroll
        for (int i = 0; i < 4; ++i) {
            const float* wi = (const float*)&w[i];
#pragma unroll
            for (int j = 0; j < 4; ++j) {
                float wv = wi[j];
                acc[i][0] += wv * v[j].x; acc[i][1] += wv * v[j].y;
                acc[i][2] += wv * v[j].z; acc[i][3] += wv * v[j].w;
            }
        }
    }
    float* Up = Upart + ((size_t)ms * NB + b) * UPSZ;
#pragma unroll
    for (int i = 0; i < 4; ++i)
        *(float4*)&Up[(kg + 32 * i) * 32 + d0] =
            make_float4(acc[i][0], acc[i][1], acc[i][2], acc[i][3]);
}

// ---------------------------------------------------------------------------
// Reduce MS partials into final U + bias row fb2^T @ V. grid (NB, 9) x 256.
__global__ __launch_bounds__(256) void k_Ured(const float* __restrict__ Upart,
                                              const float* __restrict__ V,
                                              const float* __restrict__ fb2,
                                              float* __restrict__ U) {
    int b = blockIdx.x, y = blockIdx.y;
    int tid = threadIdx.x;
    if (y < 8) {
        if (tid < 128) {
            int i4 = y * 128 + tid;            // UPSZ/4 = 1024 = 8*128
            float4 s = ((const float4*)(Upart + (size_t)b * UPSZ))[i4];
#pragma unroll
            for (int ms = 1; ms < MS; ++ms) {
                float4 v = ((const float4*)(Upart + ((size_t)ms * NB + b) * UPSZ))[i4];
                s.x += v.x; s.y += v.y; s.z += v.z; s.w += v.w;
            }
            ((float4*)(U + (size_t)b * USIZE))[i4] = s;
        }
    } else {
        __shared__ float red[8][33];
        int d = tid & 31, seg = tid >> 5;
        float ca = 0.f;
        for (int m = seg * 256; m < seg * 256 + 256; ++m)
            ca += fb2[m] * V[((size_t)b * NVEC + m) * NDIM + d];
        red[seg][d] = ca;
        __syncthreads();
        if (tid < 32) {
            float s = 0.f;
#pragma unroll
            for (int j = 0; j < 8; ++j) s += red[j][tid];
            U[(size_t)b * USIZE + 128 * 32 + tid] = s;
        }
    }
}

// ---------------------------------------------------------------------------
// Fused h+apply, 128-row block. grid (NVEC/128, NB) x 256, 1 block/CU.
// h-phase: thread 4r(interleaved) x 16k; per 4-d step 20 LDS instr / 256 FMA.
// apply:   thread 4r x 8d x k-half; per 4-k step 12 LDS instr / 128 FMA;
//          k-halves merged through LDS (reusing xs). All LDS patterns
//          bank-uniform (strides 132/36, lane-contiguous rows) or broadcast.
// LDS 119.4 KB -> 1 block/CU. LAST: classifier fused.
template <bool LAST>
__global__ __launch_bounds__(256) void k_applyF(const float* __restrict__ X,
                                                const float* __restrict__ fw1l,
                                                const float* __restrict__ fb1l,
                                                const float* __restrict__ U,
                                                float* __restrict__ Vout,
                                                const float* __restrict__ Wf,
                                                float* __restrict__ out) {
    __shared__ float hs[128 * 132];   // [r][k] pad 132, 67.6 KB
    __shared__ float xs[128 * 36];    // [r][d] pad 36, 18.4 KB (reused as merge buf)
    __shared__ float w1s[32 * 132];   // [d][k] pad 132, 16.9 KB
    __shared__ float Us[USIZE];       // [k][d] linear, broadcast reads, 16.5 KB
    int ng = blockIdx.x, b = blockIdx.y;
    int tid = threadIdx.x;
    int n0 = ng * 128;

    for (int i4 = tid; i4 < USIZE / 4; i4 += 256)
        ((float4*)Us)[i4] = ((const float4*)(U + (size_t)b * USIZE))[i4];
    {   // w1s [d][k] pad 132
        int d = tid >> 3, kc = (tid & 7) * 16;
        const float4* wg = (const float4*)(fw1l + d * NHID + kc);
        float4* wsp = (float4*)(w1s + d * 132 + kc);
#pragma unroll
        for (int q = 0; q < 4; ++q) wsp[q] = wg[q];
    }
    {   // xs [r][d] pad 36
        int r = tid >> 1, c = (tid & 1) * 16;
        const float4* xg = (const float4*)(X + ((size_t)b * NVEC + n0 + r) * NDIM + c);
        float4* xsp = (float4*)(xs + r * 36 + c);
#pragma unroll
        for (int q = 0; q < 4; ++q) xsp[q] = xg[q];
    }
    __syncthreads();

    {   // ---- h = gelu(X@fw1 + fb1): thread = 4 interleaved rows x 16 k
        int rg = tid & 31, k0 = (tid >> 5) * 16;
        float acc[4][16];
        {
            float4 bq[4];
#pragma unroll
            for (int q = 0; q < 4; ++q) bq[q] = *(const float4*)&fb1l[k0 + 4 * q];
#pragma unroll
            for (int r = 0; r < 4; ++r)
#pragma unroll
                for (int q = 0; q < 4; ++q) {
                    acc[r][4 * q + 0] = bq[q].x; acc[r][4 * q + 1] = bq[q].y;
                    acc[r][4 * q + 2] = bq[q].z; acc[r][4 * q + 3] = bq[q].w;
                }
        }
        for (int d = 0; d < NDIM; d += 4) {
            float4 xr[4];
#pragma unroll
            for (int r = 0; r < 4; ++r)
                xr[r] = *(const float4*)&xs[(rg + 32 * r) * 36 + d];   // uniform banks
#pragma unroll
            for (int dd = 0; dd < 4; ++dd) {
                float4 w0 = *(const float4*)&w1s[(d + dd) * 132 + k0];       // broadcast
                float4 w1 = *(const float4*)&w1s[(d + dd) * 132 + k0 + 4];
                float4 w2 = *(const float4*)&w1s[(d + dd) * 132 + k0 + 8];
                float4 w3 = *(const float4*)&w1s[(d + dd) * 132 + k0 + 12];
                float wk[16] = {w0.x, w0.y, w0.z, w0.w, w1.x, w1.y, w1.z, w1.w,
                                w2.x, w2.y, w2.z, w2.w, w3.x, w3.y, w3.z, w3.w};
#pragma unroll
                for (int r = 0; r < 4; ++r) {
                    float xv = ((const float*)&xr[r])[dd];
#pragma unroll
                    for (int j = 0; j < 16; ++j) acc[r][j] += xv * wk[j];
                }
            }
        }
#pragma unroll
        for (int r = 0; r < 4; ++r) {
            int row = rg + 32 * r;
#pragma unroll
            for (int q = 0; q < 4; ++q) {
                float4 o;
                o.x = gelu_fast(acc[r][4 * q + 0]);
                o.y = gelu_fast(acc[r][4 * q + 1]);
                o.z = gelu_fast(acc[r][4 * q + 2]);
                o.w = gelu_fast(acc[r][4 * q + 3]);
                *(float4*)&hs[row * 132 + k0 + 4 * q] = o;   // uniform banks
            }
        }
    }
    __syncthreads();

    {   // ---- apply: V_new = h @ U + U[128,:]; thread = 4r x 8d x k-half
        int rg = tid & 31, dg = (tid >> 5) & 3, kh = tid >> 7;
        int d0 = dg * 8, kbase = kh * 64;
        float acc2[4][8];
#pragma unroll
        for (int r = 0; r < 4; ++r)
#pragma unroll
            for (int j = 0; j < 8; ++j) acc2[r][j] = 0.f;

        for (int ks = 0; ks < 64; ks += 4) {
            int kk = kbase + ks;
            float4 hq[4];
#pragma unroll
            for (int r = 0; r < 4; ++r)
                hq[r] = *(const float4*)&hs[(rg + 32 * r) * 132 + kk];  // uniform banks
            float4 u[4][2];
#pragma unroll
            for (int j = 0; j < 4; ++j) {
                u[j][0] = *(const float4*)&Us[(kk + j) * 32 + d0];      // broadcast
                u[j][1] = *(const float4*)&Us[(kk + j) * 32 + d0 + 4];
            }
#pragma unroll
            for (int r = 0; r < 4; ++r) {
                const float* hf = (const float*)&hq[r];
#pragma unroll
                for (int j = 0; j < 4; ++j) {
                    float hv = hf[j];
                    acc2[r][0] += hv * u[j][0].x;
                    acc2[r][1] += hv * u[j][0].y;
                    acc2[r][2] += hv * u[j][0].z;
                    acc2[r][3] += hv * u[j][0].w;
                    acc2[r][4] += hv * u[j][1].x;
                    acc2[r][5] += hv * u[j][1].y;
                    acc2[r][6] += hv * u[j][1].z;
                    acc2[r][7] += hv * u[j][1].w;
                }
            }
        }

        float* part = xs;                    // xs dead after h-phase
        if (kh == 1) {
#pragma unroll
            for (int r = 0; r < 4; ++r) {
                float* p = &part[(rg + 32 * r) * 36 + d0];
                *(float4*)p       = make_float4(acc2[r][0], acc2[r][1], acc2[r][2], acc2[r][3]);
                *(float4*)(p + 4) = make_float4(acc2[r][4], acc2[r][5], acc2[r][6], acc2[r][7]);
            }
        }
        __syncthreads();
        if (kh == 0) {
            float4 ub0 = *(const float4*)&Us[128 * 32 + d0];        // broadcast
            float4 ub1 = *(const float4*)&Us[128 * 32 + d0 + 4];
#pragma unroll
            for (int r = 0; r < 4; ++r) {
                const float* p = &part[(rg + 32 * r) * 36 + d0];
                float4 p0 = *(const float4*)p;
                float4 p1 = *(const float4*)(p + 4);
                acc2[r][0] += p0.x + ub0.x; acc2[r][1] += p0.y + ub0.y;
                acc2[r][2] += p0.z + ub0.z; acc2[r][3] += p0.w + ub0.w;
                acc2[r][4] += p1.x + ub1.x; acc2[r][5] += p1.y + ub1.y;
                acc2[r][6] += p1.z + ub1.z; acc2[r][7] += p1.w + ub1.w;
            }
            if constexpr (!LAST) {
#pragma unroll
                for (int r = 0; r < 4; ++r) {
                    float* vo = Vout + ((size_t)b * NVEC + n0 + rg + 32 * r) * NDIM + d0;
                    *(float4*)vo       = make_float4(acc2[r][0], acc2[r][1], acc2[r][2], acc2[r][3]);
                    *(float4*)(vo + 4) = make_float4(acc2[r][4], acc2[r][5], acc2[r][6], acc2[r][7]);
                }
            } else {
                float accC[NCLASS];
#pragma unroll
                for (int c = 0; c < NCLASS; ++c) accC[c] = 0.f;
#pragma unroll
                for (int r = 0; r < 4; ++r) {
                    int nrow = n0 + rg + 32 * r;
#pragma unroll
                    for (int dd = 0; dd < 8; ++dd) {
                        float v = acc2[r][dd];
                        const float2* wr =
                            (const float2*)(Wf + ((size_t)nrow * 32 + d0 + dd) * NCLASS);
#pragma unroll
                        for (int p = 0; p < 5; ++p) {
                            float2 w = wr[p];
                            accC[2 * p]     += v * w.x;
                            accC[2 * p + 1] += v * w.y;
                        }
                    }
                }
#pragma unroll
                for (int c = 0; c < NCLASS; ++c)
#pragma unroll
                    for (int off = 32; off >= 1; off >>= 1)
                        accC[c] += __shfl_down(accC[c], off, 64);
                if ((tid & 63) == 0) {
#pragma unroll
                    for (int c = 0; c < NCLASS; ++c)
                        atomicAdd(&out[b * NCLASS + c], accC[c]);
                }
            }
        }
    }
}

// ---------------------------------------------------------------------------
extern "C" void kernel_launch(void* const* d_in, const int* in_sizes, int n_in,
                              void* d_out, int out_size, void* d_ws, size_t ws_size,
                              hipStream_t stream) {
    const int*   data = (const int*)d_in[0];
    const float* emb  = (const float*)d_in[1];
    const float* fw1  = (const float*)d_in[2];
    const float* fb1  = (const float*)d_in[3];
    const float* fw2  = (const float*)d_in[4];
    const float* fb2  = (const float*)d_in[5];
    const float* Wf   = (const float*)d_in[6];
    const float* bf   = (const float*)d_in[7];
    float* out = (float*)d_out;

    float* X     = (float*)d_ws;                      // 1048576 floats
    float* VA    = X + NB * NVEC * NDIM;              // 1048576
    float* VB    = VA + NB * NVEC * NDIM;             // 1048576
    float* Upart = VB + NB * NVEC * NDIM;             // MS*NB*UPSZ = 1048576
    float* U     = Upart + (size_t)MS * NB * UPSZ;    // NB*USIZE = 66048

    k_embed<<<dim3(NB * NVEC * NDIM / 4 / 256), 256, 0, stream>>>(data, emb, bf, X, out);

    const float* Vcur = X;
    float* Vnext = VA;
    for (int t = 0; t < NW; ++t) {
        int i = NW - 1 - t;
        k_U<<<dim3(MS, NB), 256, 0, stream>>>(Vcur, fw2 + (size_t)i * NHID * NVEC, Upart);
        k_Ured<<<dim3(NB, 9), 256, 0, stream>>>(Upart, Vcur, fb2 + (size_t)i * NVEC, U);
        if (i > 0) {
            k_applyF<false><<<dim3(NVEC / 128, NB), 256, 0, stream>>>(
                X, fw1 + (size_t)i * NDIM * NHID, fb1 + (size_t)i * NHID,
                U, Vnext, nullptr, nullptr);
            Vcur = Vnext;
            Vnext = (Vnext == VA) ? VB : VA;
        } else {
            k_applyF<true><<<dim3(NVEC / 128, NB), 256, 0, stream>>>(
                X, fw1, fb1, U, nullptr, Wf, out);
        }
    }
}